// Round 3
// baseline (28.210 us; speedup 1.0000x reference)
//
#include <hip/hip_runtime.h>

// Problem constants (match reference)
#define BATCH    128
#define NEV      16
#define NS       32768
#define STEP     256
#define TILE     1024                 // floats per tile
#define NTILES   (NS / TILE)          // 32 tiles per batch
// Block layout: 512 threads, 8 tiles per block = pairs {r, r+4, r+8, r+12}
// with both tiles of each pair. Stride-4 pair grouping makes per-block load
// volume ~independent of every event's start s (clamp-transition classes are
// distributed one-per-block), killing the straggler tail.

__global__ __launch_bounds__(512)
void summarizer_gather_kernel(const float* __restrict__ x,
                              const int* __restrict__ idx,
                              float* __restrict__ out)
{
    const int r = blockIdx.x & 3;            // pair-group 0..3
    const int b = blockIdx.x >> 2;           // batch

    const int half = (int)threadIdx.x >> 8;  // 0: even slots early; 1: swapped
    const int lane = (int)threadIdx.x & 255; // position within a tile (x4)

    const float* xb = x + (size_t)b * NEV * NS;
    const int*   ib = idx + b * NEV;         // block-uniform -> s_load

    // Four output positions, one in each of 4 tile-pairs; alternate early/late
    // across slots so each thread's total work is balanced too.
    int t[4];
    #pragma unroll
    for (int k = 0; k < 4; ++k) {
        const int p    = r + 4 * k;                          // pair index 0..15
        const int tile = ((k + half) & 1) ? (NTILES - 1 - p) : p;
        t[k] = tile * TILE + lane * 4;
    }

    float4 acc0 = make_float4(0.f, 0.f, 0.f, 0.f);
    float4 acc1 = make_float4(0.f, 0.f, 0.f, 0.f);
    float4 acc2 = make_float4(0.f, 0.f, 0.f, 0.f);
    float4 acc3 = make_float4(0.f, 0.f, 0.f, 0.f);

    // Starts are multiples of 256; each wave's 64 lanes x float4 span exactly
    // 256 contiguous 256-aligned samples (waves never straddle the 256-thread
    // halves) -> every (t >= s) predicate is wave-uniform. Skipped loads cost
    // zero bandwidth and zero divergence.
    #pragma unroll
    for (int i = 0; i < NEV; ++i) {
        const int s = ib[i] * STEP;
        const float* xe = xb + (size_t)i * NS - s;
        if (t[0] >= s) {
            const float4 v = *reinterpret_cast<const float4*>(xe + t[0]);
            acc0.x += v.x; acc0.y += v.y; acc0.z += v.z; acc0.w += v.w;
        }
        if (t[1] >= s) {
            const float4 v = *reinterpret_cast<const float4*>(xe + t[1]);
            acc1.x += v.x; acc1.y += v.y; acc1.z += v.z; acc1.w += v.w;
        }
        if (t[2] >= s) {
            const float4 v = *reinterpret_cast<const float4*>(xe + t[2]);
            acc2.x += v.x; acc2.y += v.y; acc2.z += v.z; acc2.w += v.w;
        }
        if (t[3] >= s) {
            const float4 v = *reinterpret_cast<const float4*>(xe + t[3]);
            acc3.x += v.x; acc3.y += v.y; acc3.z += v.z; acc3.w += v.w;
        }
    }

    float* ob = out + (size_t)b * NS;
    *reinterpret_cast<float4*>(ob + t[0]) = acc0;
    *reinterpret_cast<float4*>(ob + t[1]) = acc1;
    *reinterpret_cast<float4*>(ob + t[2]) = acc2;
    *reinterpret_cast<float4*>(ob + t[3]) = acc3;
}

extern "C" void kernel_launch(void* const* d_in, const int* in_sizes, int n_in,
                              void* d_out, int out_size, void* d_ws, size_t ws_size,
                              hipStream_t stream)
{
    const float* x   = (const float*)d_in[0];   // [128, 16, 32768] f32
    const int*   idx = (const int*)d_in[1];     // [128, 16] int32
    float*       out = (float*)d_out;           // [128, 1, 32768] f32

    const int grid = BATCH * 4;                 // 512 blocks = 2 blocks/CU exact
    summarizer_gather_kernel<<<grid, 512, 0, stream>>>(x, idx, out);
}